// Round 1
// baseline (107.790 us; speedup 1.0000x reference)
//
#include <hip/hip_runtime.h>
#include <math.h>

// Problem constants
#define NCLS   100
#define BATCH_ 2048
#define OK     9        // POLICY_NUMS + 2
#define FHALF  64       // FEATURE_NUMS / 2

#define NLOGB  128      // logits blocks: 1024 thr = 16 waves, 1 row/wave
#define NPOLB  16       // policy blocks: wave 0 handles 64 pair-rows
#define NBLK   (NLOGB + NPOLB)

// Workspace layout (floats). Every slot below is written exactly once by its
// owning block (plain stores); the last-arriving block reduces.
#define LP_OFF 0                        // 128 x {ce, kl}
#define PS_OFF (LP_OFF + NLOGB * 2)     // 16 x 72 policy stats
#define PB_OFF (PS_OFF + NPOLB * 72)    // 16 x 320 policy buckets

// Module-scope arrival counter: initialized 0 at module load, and the last
// block resets it to 0 before combining, so every launch (incl. graph replay)
// starts from a known state. NOT in d_ws, so the harness poison can't touch it.
__device__ int g_arrive = 0;

__device__ __forceinline__ float waveSum(float v) {
#pragma unroll
    for (int off = 32; off; off >>= 1) v += __shfl_xor(v, off, 64);
    return v;
}
__device__ __forceinline__ float waveMax(float v) {
#pragma unroll
    for (int off = 32; off; off >>= 1) v = fmaxf(v, __shfl_xor(v, off, 64));
    return v;
}

__global__ __launch_bounds__(1024) void fused_kernel(
        const float* __restrict__ slog, const float* __restrict__ tlog,
        const float* __restrict__ spol, const float* __restrict__ tpol,
        const float* __restrict__ W1,   const float* __restrict__ W2,
        const int*   __restrict__ tgt,
        const float* __restrict__ bias1, const float* __restrict__ bias2,
        float* __restrict__ ws, float* __restrict__ out)
{
    __shared__ float bkt[320];
    __shared__ float redL[32];
    // combine-phase scratch (only the last block uses these)
    __shared__ float statsC[72];
    __shared__ float bktC[320];
    __shared__ float cekl[8];
    __shared__ int   lastFlag;

    const int tid  = threadIdx.x;
    const int wave = tid >> 6;
    const int lane = tid & 63;

    if (blockIdx.x < NLOGB) {
        // ---------- logits: CE + KL(T=4), one wave per row, 16 rows/block ----------
        const int r = blockIdx.x * 16 + wave;              // 0..2047
        const float* x = slog + r * NCLS;
        const float* y = tlog + r * NCLS;
        const int label = tgt[r * 8];                      // start indirect chain early
        const bool has2 = lane < (NCLS - 64);
        float x1 = x[lane];
        float y1 = y[lane];
        float x2 = has2 ? x[lane + 64] : -3.0e38f;
        float y2 = has2 ? y[lane + 64] : -3.0e38f;
        float xl = x[label];
        float mx = waveMax(fmaxf(x1, x2));
        float my = waveMax(fmaxf(y1, y2));
        float se1  = waveSum(expf(x1 - mx) + (has2 ? expf(x2 - mx) : 0.f));
        float se4s = waveSum(expf((x1 - mx) * 0.25f) + (has2 ? expf((x2 - mx) * 0.25f) : 0.f));
        float e1 = expf((y1 - my) * 0.25f);
        float e2 = has2 ? expf((y2 - my) * 0.25f) : 0.f;
        float se4t = waveSum(e1 + e2);
        float tnum = waveSum(e1 * (y1 - x1) * 0.25f + (has2 ? e2 * (y2 - x2) * 0.25f : 0.f));
        if (lane == 0) {
            float logZ1  = mx + logf(se1);
            float logZ4s = mx * 0.25f + logf(se4s);
            float logZ4t = my * 0.25f + logf(se4t);
            redL[wave * 2]     = logZ1 - xl;
            redL[wave * 2 + 1] = tnum / se4t + logZ4s - logZ4t;
        }
        __syncthreads();
        if (tid < 2) {
            float s = 0.f;
#pragma unroll
            for (int w = 0; w < 16; ++w) s += redL[w * 2 + tid];
            ws[LP_OFF + blockIdx.x * 2 + tid] = s;
        }
    } else {
        // ---------- policy: pair-linear closed-form stats (wave 0 only) ----------
        // Weights are read DIRECTLY from global with wave-uniform addresses:
        // the compiler can scalarize to s_load (constant cache), removing the
        // LDS staging pass and ~2300 ds_read_b32 from the critical path.
        const int pb = blockIdx.x - NLOGB;                 // 0..15
        if (tid < 320) bkt[tid] = 0.f;
        __syncthreads();

        float As[OK], Bs[OK];
        if (tid < 64) {
            const int i = pb * 64 + tid;                   // pair-row 0..1023
            const float4* f1s = (const float4*)(spol + (2 * i) * FHALF);
            const float4* f2s = (const float4*)(spol + (2 * i + 1) * FHALF);
            const float4* f1t = (const float4*)(tpol + (2 * i) * FHALF);
            const float4* f2t = (const float4*)(tpol + (2 * i + 1) * FHALF);
            const float4* w1q = (const float4*)W1;         // [OK][32] float4s
            const float4* w2q = (const float4*)W2;

            float At[OK], Bt[OK];
#pragma unroll
            for (int k = 0; k < OK; ++k) { As[k] = 0.f; Bs[k] = 0.f; At[k] = 0.f; Bt[k] = 0.f; }
            for (int f4 = 0; f4 < FHALF / 4; ++f4) {
                float4 a4 = f1s[f4], b4 = f2s[f4], c4 = f1t[f4], d4 = f2t[f4];
#pragma unroll
                for (int k = 0; k < OK; ++k) {
                    const float4 wa2 = w2q[k * 32 + f4];
                    const float4 wb2 = w2q[k * 32 + 16 + f4];
                    const float4 wa1 = w1q[k * 32 + f4];
                    const float4 wb1 = w1q[k * 32 + 16 + f4];
                    As[k] = fmaf(a4.x, wa2.x, As[k]);
                    As[k] = fmaf(a4.y, wa2.y, As[k]);
                    As[k] = fmaf(a4.z, wa2.z, As[k]);
                    As[k] = fmaf(a4.w, wa2.w, As[k]);
                    Bs[k] = fmaf(b4.x, wb2.x, Bs[k]);
                    Bs[k] = fmaf(b4.y, wb2.y, Bs[k]);
                    Bs[k] = fmaf(b4.z, wb2.z, Bs[k]);
                    Bs[k] = fmaf(b4.w, wb2.w, Bs[k]);
                    At[k] = fmaf(c4.x, wa1.x, At[k]);
                    At[k] = fmaf(c4.y, wa1.y, At[k]);
                    At[k] = fmaf(c4.z, wa1.z, At[k]);
                    At[k] = fmaf(c4.w, wa1.w, At[k]);
                    Bt[k] = fmaf(d4.x, wb1.x, Bt[k]);
                    Bt[k] = fmaf(d4.y, wb1.y, Bt[k]);
                    Bt[k] = fmaf(d4.z, wb1.z, Bt[k]);
                    Bt[k] = fmaf(d4.w, wb1.w, Bt[k]);
                }
            }

#pragma unroll
            for (int k = 0; k < OK; ++k) {
                float du = Bs[k] - Bt[k], dw = As[k] - At[k];
                float v0 = waveSum(du),     v1 = waveSum(du * du);
                float v2 = waveSum(dw),     v3 = waveSum(dw * dw);
                float v4 = waveSum(Bs[k]),  v5 = waveSum(Bs[k] * Bs[k]);
                float v6 = waveSum(As[k]),  v7 = waveSum(As[k] * As[k]);
                if (lane == 0) {
                    float* p = ws + PS_OFF + pb * 72 + k * 8;
                    p[0] = v0; p[1] = v1; p[2] = v2; p[3] = v3;
                    p[4] = v4; p[5] = v5; p[6] = v6; p[7] = v7;
                }
            }

            const int* t1r = tgt + (2 * i) * 8;
            const int* t2r = tgt + (2 * i + 1) * 8;
#pragma unroll
            for (int c0 = 0; c0 < 8; ++c0) {
                int v1i = t1r[c0], v2i = t2r[c0];
                atomicAdd(&bkt[0 * 80 + c0 * 10 + v1i], 1.0f);
                atomicAdd(&bkt[1 * 80 + c0 * 10 + v2i], 1.0f);
                atomicAdd(&bkt[2 * 80 + c0 * 10 + v1i], As[c0 + 1]);
                atomicAdd(&bkt[3 * 80 + c0 * 10 + v2i], Bs[c0 + 1]);
            }
        }
        __syncthreads();
        if (tid < 320) ws[PB_OFF + pb * 320 + tid] = bkt[tid];
    }

    // ---------- last-block combine (replaces the second kernel launch) ----------
    // __syncthreads drains every wave's global stores (vmcnt(0) before s_barrier);
    // tid0's __threadfence is the device-scope release; atomicAdd is device-scope.
    __syncthreads();
    if (tid == 0) {
        __threadfence();
        int old = atomicAdd(&g_arrive, 1);
        int last = (old == NBLK - 1);
        if (last) {
            g_arrive = 0;          // re-arm for next launch / graph replay
            __threadfence();       // acquire: invalidate stale L1/L2 before ws reads
        }
        lastFlag = last;
    }
    __syncthreads();
    if (!lastFlag) return;

    // --- combine phase, executed by the single last-arriving block ---
    float ce = 0.f, kl = 0.f;
    if (tid < NLOGB) {
        ce = ws[LP_OFF + tid * 2];
        kl = ws[LP_OFF + tid * 2 + 1];
    }
    ce = waveSum(ce); kl = waveSum(kl);
    if (lane == 0 && wave < 2) { cekl[wave * 2] = ce; cekl[wave * 2 + 1] = kl; }

    if (tid < 72) {
        float s = 0.f;
#pragma unroll
        for (int b = 0; b < NPOLB; ++b) s += ws[PS_OFF + b * 72 + tid];
        statsC[tid] = s;
    }
    if (tid < 320) {
        float s = 0.f;
#pragma unroll
        for (int b = 0; b < NPOLB; ++b) s += ws[PB_OFF + b * 320 + tid];
        bktC[tid] = s;
    }
    __syncthreads();

    if (tid == 0) {
        const double N = 1024.0, M = 1048576.0;
        double ce_main = (double)(cekl[0] + cekl[2]) / (double)BATCH_;
        double kl_main = (double)(cekl[1] + cekl[3]) * 16.0
                       / (double)(BATCH_ * NCLS);

        double kl_pol = 0.0, Sp_acc = 0.0;
        double SumL[OK], SumL2[OK];
        for (int k = 0; k < OK; ++k) {
            const float* p = &statsC[k * 8];
            double D1u = p[0], D2u = p[1], D1w = p[2], D2w = p[3];
            double U1 = p[4], U2 = p[5], Wa1 = p[6], Wa2 = p[7];
            double cd = (double)bias2[k] - (double)bias1[k];
            double b  = (double)bias2[k];
            double S = N * D2u + N * (D2w + 2.0 * cd * D1w + N * cd * cd)
                     + 2.0 * D1u * (D1w + N * cd);
            if (k == 0)      kl_pol += S / M;
            else if (k == 1) kl_pol += 0.5 * S / M;
            else             Sp_acc += S;
            SumL[k]  = N * U1 + N * Wa1 + M * b;
            SumL2[k] = N * U2 + N * (Wa2 + 2.0 * b * Wa1 + N * b * b)
                     + 2.0 * U1 * (Wa1 + N * b);
        }
        kl_pol += 0.001 * Sp_acc / (7.0 * M);

        double ce_I = -((double)statsC[4] + (double)statsC[6] + N * (double)bias2[0]) / M;

        const float* cnt1 = &bktC[0];
        const float* cnt2 = &bktC[80];
        const float* sA   = &bktC[160];
        const float* sB   = &bktC[240];
        double ce_C = 0.0, ceP = 0.0;
        for (int c0 = 0; c0 < 8; ++c0) {
            double ms = 0.0, pc = 0.0;
            for (int v = 0; v < 10; ++v) {
                double c1 = (double)cnt1[c0 * 10 + v], c2 = (double)cnt2[c0 * 10 + v];
                ms += c1 * (double)sB[c0 * 10 + v] + c2 * (double)sA[c0 * 10 + v];
                pc += c1 * c2;
            }
            ms += (double)bias2[c0 + 1] * pc;
            if (c0 == 0) {
                ce_C = -0.5 * ms / M;
            } else {
                int k = c0 + 1;
                double sg = 2.0 * ms - SumL[k];
                ceP += SumL2[k] - 2.0 * sg + M;
            }
        }
        ceP *= 0.001 / (7.0 * M);

        out[0] = (float)(ce_main + kl_main + kl_pol + ce_I + ce_C + ceP);
    }
}

extern "C" void kernel_launch(void* const* d_in, const int* in_sizes, int n_in,
                              void* d_out, int out_size, void* d_ws, size_t ws_size,
                              hipStream_t stream) {
    const float* slog = (const float*)d_in[0];
    const float* tlog = (const float*)d_in[1];
    const float* spol = (const float*)d_in[2];
    const float* tpol = (const float*)d_in[3];
    const float* W1   = (const float*)d_in[4];
    const float* b1   = (const float*)d_in[5];
    const float* W2   = (const float*)d_in[6];
    const float* b2   = (const float*)d_in[7];
    const int*   tgt  = (const int*)d_in[8];
    float* ws = (float*)d_ws;

    fused_kernel<<<NBLK, 1024, 0, stream>>>(slog, tlog, spol, tpol, W1, W2, tgt,
                                            b1, b2, ws, (float*)d_out);
}

// Round 2
// 95.421 us; speedup vs baseline: 1.1296x; 1.1296x over previous
//
#include <hip/hip_runtime.h>
#include <math.h>

// Problem constants
#define NCLS   100
#define BATCH_ 2048
#define OK     9        // POLICY_NUMS + 2
#define FHALF  64       // FEATURE_NUMS / 2

#define NLOGB  128      // logits blocks: 1024 thr = 16 waves, 1 row/wave
#define NPOLB  16       // policy blocks: wave 0 handles 64 pair-rows
#define NBLK   (NLOGB + NPOLB)

// Workspace layout (floats). Every slot below is written exactly once by its
// owning block (plain stores); the last-arriving block reduces.
#define LP_OFF 0                        // 128 x {ce, kl}
#define PS_OFF (LP_OFF + NLOGB * 2)     // 16 x 72 policy stats
#define PB_OFF (PS_OFF + NPOLB * 72)    // 16 x 320 policy buckets

// Module-scope arrival counter: initialized 0 at module load; the last block
// resets it to 0 before combining, so every launch (incl. graph replay)
// starts from a known state. NOT in d_ws, so the harness poison can't touch it.
__device__ int g_arrive = 0;

__device__ __forceinline__ float waveSum(float v) {
#pragma unroll
    for (int off = 32; off; off >>= 1) v += __shfl_xor(v, off, 64);
    return v;
}
__device__ __forceinline__ float waveMax(float v) {
#pragma unroll
    for (int off = 32; off; off >>= 1) v = fmaxf(v, __shfl_xor(v, off, 64));
    return v;
}

__global__ __launch_bounds__(1024) void fused_kernel(
        const float* __restrict__ slog, const float* __restrict__ tlog,
        const float* __restrict__ spol, const float* __restrict__ tpol,
        const float* __restrict__ W1,   const float* __restrict__ W2,
        const int*   __restrict__ tgt,
        const float* __restrict__ bias1, const float* __restrict__ bias2,
        float* __restrict__ ws, float* __restrict__ out)
{
    // policy-phase LDS: weights as float4 so reads are ds_read_b128
    __shared__ float4 w1s4[OK * 32];    // [OK][32] float4  (= [OK][128] floats)
    __shared__ float4 w2s4[OK * 32];
    __shared__ float bkt[320];
    __shared__ float redL[32];
    // combine-phase scratch (only the last block uses these)
    __shared__ float statsC[72];
    __shared__ float bktC[320];
    __shared__ float cekl[8];
    __shared__ int   lastFlag;

    const int tid  = threadIdx.x;
    const int wave = tid >> 6;
    const int lane = tid & 63;

    if (blockIdx.x < NLOGB) {
        // ---------- logits: CE + KL(T=4), one wave per row, 16 rows/block ----------
        const int r = blockIdx.x * 16 + wave;              // 0..2047
        const float* x = slog + r * NCLS;
        const float* y = tlog + r * NCLS;
        const int label = tgt[r * 8];                      // start indirect chain early
        const bool has2 = lane < (NCLS - 64);
        float x1 = x[lane];
        float y1 = y[lane];
        float x2 = has2 ? x[lane + 64] : -3.0e38f;
        float y2 = has2 ? y[lane + 64] : -3.0e38f;
        float xl = x[label];
        float mx = waveMax(fmaxf(x1, x2));
        float my = waveMax(fmaxf(y1, y2));
        float se1  = waveSum(expf(x1 - mx) + (has2 ? expf(x2 - mx) : 0.f));
        float se4s = waveSum(expf((x1 - mx) * 0.25f) + (has2 ? expf((x2 - mx) * 0.25f) : 0.f));
        float e1 = expf((y1 - my) * 0.25f);
        float e2 = has2 ? expf((y2 - my) * 0.25f) : 0.f;
        float se4t = waveSum(e1 + e2);
        float tnum = waveSum(e1 * (y1 - x1) * 0.25f + (has2 ? e2 * (y2 - x2) * 0.25f : 0.f));
        if (lane == 0) {
            float logZ1  = mx + logf(se1);
            float logZ4s = mx * 0.25f + logf(se4s);
            float logZ4t = my * 0.25f + logf(se4t);
            redL[wave * 2]     = logZ1 - xl;
            redL[wave * 2 + 1] = tnum / se4t + logZ4s - logZ4t;
        }
        __syncthreads();
        if (tid < 2) {
            float s = 0.f;
#pragma unroll
            for (int w = 0; w < 16; ++w) s += redL[w * 2 + tid];
            ws[LP_OFF + blockIdx.x * 2 + tid] = s;
        }
    } else {
        // ---------- policy: pair-linear closed-form stats (wave 0 only) ----------
        const int pb = blockIdx.x - NLOGB;                 // 0..15
        // cooperative stage: 288 float4 per weight matrix, coalesced 16B loads
        if (tid < OK * 32) {
            w1s4[tid] = ((const float4*)W1)[tid];
            w2s4[tid] = ((const float4*)W2)[tid];
        }
        if (tid < 320) bkt[tid] = 0.f;
        __syncthreads();

        float As[OK], Bs[OK];
        if (tid < 64) {
            const int i = pb * 64 + tid;                   // pair-row 0..1023
            const float4* f1s = (const float4*)(spol + (2 * i) * FHALF);
            const float4* f2s = (const float4*)(spol + (2 * i + 1) * FHALF);
            const float4* f1t = (const float4*)(tpol + (2 * i) * FHALF);
            const float4* f2t = (const float4*)(tpol + (2 * i + 1) * FHALF);

            float At[OK], Bt[OK];
#pragma unroll
            for (int k = 0; k < OK; ++k) { As[k] = 0.f; Bs[k] = 0.f; At[k] = 0.f; Bt[k] = 0.f; }
            for (int f4 = 0; f4 < FHALF / 4; ++f4) {
                float4 a4 = f1s[f4], b4 = f2s[f4], c4 = f1t[f4], d4 = f2t[f4];
#pragma unroll
                for (int k = 0; k < OK; ++k) {
                    // wave-uniform LDS addresses -> broadcast ds_read_b128, no conflicts
                    const float4 wa2 = w2s4[k * 32 + f4];
                    const float4 wb2 = w2s4[k * 32 + 16 + f4];
                    const float4 wa1 = w1s4[k * 32 + f4];
                    const float4 wb1 = w1s4[k * 32 + 16 + f4];
                    As[k] = fmaf(a4.x, wa2.x, As[k]);
                    As[k] = fmaf(a4.y, wa2.y, As[k]);
                    As[k] = fmaf(a4.z, wa2.z, As[k]);
                    As[k] = fmaf(a4.w, wa2.w, As[k]);
                    Bs[k] = fmaf(b4.x, wb2.x, Bs[k]);
                    Bs[k] = fmaf(b4.y, wb2.y, Bs[k]);
                    Bs[k] = fmaf(b4.z, wb2.z, Bs[k]);
                    Bs[k] = fmaf(b4.w, wb2.w, Bs[k]);
                    At[k] = fmaf(c4.x, wa1.x, At[k]);
                    At[k] = fmaf(c4.y, wa1.y, At[k]);
                    At[k] = fmaf(c4.z, wa1.z, At[k]);
                    At[k] = fmaf(c4.w, wa1.w, At[k]);
                    Bt[k] = fmaf(d4.x, wb1.x, Bt[k]);
                    Bt[k] = fmaf(d4.y, wb1.y, Bt[k]);
                    Bt[k] = fmaf(d4.z, wb1.z, Bt[k]);
                    Bt[k] = fmaf(d4.w, wb1.w, Bt[k]);
                }
            }

#pragma unroll
            for (int k = 0; k < OK; ++k) {
                float du = Bs[k] - Bt[k], dw = As[k] - At[k];
                float v0 = waveSum(du),     v1 = waveSum(du * du);
                float v2 = waveSum(dw),     v3 = waveSum(dw * dw);
                float v4 = waveSum(Bs[k]),  v5 = waveSum(Bs[k] * Bs[k]);
                float v6 = waveSum(As[k]),  v7 = waveSum(As[k] * As[k]);
                if (lane == 0) {
                    float* p = ws + PS_OFF + pb * 72 + k * 8;
                    p[0] = v0; p[1] = v1; p[2] = v2; p[3] = v3;
                    p[4] = v4; p[5] = v5; p[6] = v6; p[7] = v7;
                }
            }

            const int* t1r = tgt + (2 * i) * 8;
            const int* t2r = tgt + (2 * i + 1) * 8;
#pragma unroll
            for (int c0 = 0; c0 < 8; ++c0) {
                int v1i = t1r[c0], v2i = t2r[c0];
                atomicAdd(&bkt[0 * 80 + c0 * 10 + v1i], 1.0f);
                atomicAdd(&bkt[1 * 80 + c0 * 10 + v2i], 1.0f);
                atomicAdd(&bkt[2 * 80 + c0 * 10 + v1i], As[c0 + 1]);
                atomicAdd(&bkt[3 * 80 + c0 * 10 + v2i], Bs[c0 + 1]);
            }
        }
        __syncthreads();
        if (tid < 320) ws[PB_OFF + pb * 320 + tid] = bkt[tid];
    }

    // ---------- last-block combine (replaces the second kernel launch) ----------
    // __syncthreads drains every wave's global stores (vmcnt(0) before s_barrier);
    // tid0's __threadfence is the device-scope release; atomicAdd is device-scope.
    __syncthreads();
    if (tid == 0) {
        __threadfence();
        int old = atomicAdd(&g_arrive, 1);
        int last = (old == NBLK - 1);
        if (last) {
            g_arrive = 0;          // re-arm for next launch / graph replay
            __threadfence();       // acquire before ws reads
        }
        lastFlag = last;
    }
    __syncthreads();
    if (!lastFlag) return;

    // --- combine phase, executed by the single last-arriving block ---
    float ce = 0.f, kl = 0.f;
    if (tid < NLOGB) {
        ce = ws[LP_OFF + tid * 2];
        kl = ws[LP_OFF + tid * 2 + 1];
    }
    ce = waveSum(ce); kl = waveSum(kl);
    if (lane == 0 && wave < 2) { cekl[wave * 2] = ce; cekl[wave * 2 + 1] = kl; }

    if (tid < 72) {
        float s = 0.f;
#pragma unroll
        for (int b = 0; b < NPOLB; ++b) s += ws[PS_OFF + b * 72 + tid];
        statsC[tid] = s;
    }
    if (tid < 320) {
        float s = 0.f;
#pragma unroll
        for (int b = 0; b < NPOLB; ++b) s += ws[PB_OFF + b * 320 + tid];
        bktC[tid] = s;
    }
    __syncthreads();

    if (tid == 0) {
        const double N = 1024.0, M = 1048576.0;
        double ce_main = (double)(cekl[0] + cekl[2]) / (double)BATCH_;
        double kl_main = (double)(cekl[1] + cekl[3]) * 16.0
                       / (double)(BATCH_ * NCLS);

        double kl_pol = 0.0, Sp_acc = 0.0;
        double SumL[OK], SumL2[OK];
        for (int k = 0; k < OK; ++k) {
            const float* p = &statsC[k * 8];
            double D1u = p[0], D2u = p[1], D1w = p[2], D2w = p[3];
            double U1 = p[4], U2 = p[5], Wa1 = p[6], Wa2 = p[7];
            double cd = (double)bias2[k] - (double)bias1[k];
            double b  = (double)bias2[k];
            double S = N * D2u + N * (D2w + 2.0 * cd * D1w + N * cd * cd)
                     + 2.0 * D1u * (D1w + N * cd);
            if (k == 0)      kl_pol += S / M;
            else if (k == 1) kl_pol += 0.5 * S / M;
            else             Sp_acc += S;
            SumL[k]  = N * U1 + N * Wa1 + M * b;
            SumL2[k] = N * U2 + N * (Wa2 + 2.0 * b * Wa1 + N * b * b)
                     + 2.0 * U1 * (Wa1 + N * b);
        }
        kl_pol += 0.001 * Sp_acc / (7.0 * M);

        double ce_I = -((double)statsC[4] + (double)statsC[6] + N * (double)bias2[0]) / M;

        const float* cnt1 = &bktC[0];
        const float* cnt2 = &bktC[80];
        const float* sA   = &bktC[160];
        const float* sB   = &bktC[240];
        double ce_C = 0.0, ceP = 0.0;
        for (int c0 = 0; c0 < 8; ++c0) {
            double ms = 0.0, pc = 0.0;
            for (int v = 0; v < 10; ++v) {
                double c1 = (double)cnt1[c0 * 10 + v], c2 = (double)cnt2[c0 * 10 + v];
                ms += c1 * (double)sB[c0 * 10 + v] + c2 * (double)sA[c0 * 10 + v];
                pc += c1 * c2;
            }
            ms += (double)bias2[c0 + 1] * pc;
            if (c0 == 0) {
                ce_C = -0.5 * ms / M;
            } else {
                int k = c0 + 1;
                double sg = 2.0 * ms - SumL[k];
                ceP += SumL2[k] - 2.0 * sg + M;
            }
        }
        ceP *= 0.001 / (7.0 * M);

        out[0] = (float)(ce_main + kl_main + kl_pol + ce_I + ce_C + ceP);
    }
}

extern "C" void kernel_launch(void* const* d_in, const int* in_sizes, int n_in,
                              void* d_out, int out_size, void* d_ws, size_t ws_size,
                              hipStream_t stream) {
    const float* slog = (const float*)d_in[0];
    const float* tlog = (const float*)d_in[1];
    const float* spol = (const float*)d_in[2];
    const float* tpol = (const float*)d_in[3];
    const float* W1   = (const float*)d_in[4];
    const float* b1   = (const float*)d_in[5];
    const float* W2   = (const float*)d_in[6];
    const float* b2   = (const float*)d_in[7];
    const int*   tgt  = (const int*)d_in[8];
    float* ws = (float*)d_ws;

    fused_kernel<<<NBLK, 1024, 0, stream>>>(slog, tlog, spol, tpol, W1, W2, tgt,
                                            b1, b2, ws, (float*)d_out);
}

// Round 3
// 87.817 us; speedup vs baseline: 1.2274x; 1.0866x over previous
//
#include <hip/hip_runtime.h>
#include <math.h>

// Problem constants
#define NCLS   100
#define BATCH_ 2048
#define OK     9        // POLICY_NUMS + 2
#define FHALF  64       // FEATURE_NUMS / 2

#define NLOGB  128      // logits blocks: 1024 thr = 16 waves, 1 row/wave
#define NPOLB  16       // policy blocks: 64 pair-rows each, 4 streams on waves 0-3
#define NBLK   (NLOGB + NPOLB)

// Workspace layout (floats). Every slot below is written exactly once by its
// owning block (plain stores); the last-arriving block reduces.
#define LP_OFF 0                        // 128 x {ce, kl}
#define PS_OFF (LP_OFF + NLOGB * 2)     // 16 x 72 policy stats
#define PB_OFF (PS_OFF + NPOLB * 72)    // 16 x 320 policy buckets

// Module-scope arrival counter: init 0 at module load; last block resets it
// before combining so graph replays start clean. Not in d_ws (poison-safe).
__device__ int g_arrive = 0;

__device__ __forceinline__ float waveSum(float v) {
#pragma unroll
    for (int off = 32; off; off >>= 1) v += __shfl_xor(v, off, 64);
    return v;
}
__device__ __forceinline__ float waveMax(float v) {
#pragma unroll
    for (int off = 32; off; off >>= 1) v = fmaxf(v, __shfl_xor(v, off, 64));
    return v;
}

__global__ __launch_bounds__(1024) void fused_kernel(
        const float* __restrict__ slog, const float* __restrict__ tlog,
        const float* __restrict__ spol, const float* __restrict__ tpol,
        const float* __restrict__ W1,   const float* __restrict__ W2,
        const int*   __restrict__ tgt,
        const float* __restrict__ bias1, const float* __restrict__ bias2,
        float* __restrict__ ws, float* __restrict__ out)
{
    // policy-phase LDS
    __shared__ float4 w1s4[OK * 32];        // [OK][32] float4 = [OK][128] floats
    __shared__ float4 w2s4[OK * 32];
    __shared__ float  res[4 * OK * 64];     // [stream][k][lane] per-row dot results
    __shared__ float  bkt[320];
    __shared__ float  redL[32];
    // combine-phase scratch (only the last block uses these)
    __shared__ float statsC[72];
    __shared__ float bktC[320];
    __shared__ float cekl[8];
    __shared__ int   lastFlag;

    const int tid  = threadIdx.x;
    const int wave = tid >> 6;
    const int lane = tid & 63;

    if (blockIdx.x < NLOGB) {
        // ---------- logits: CE + KL(T=4), one wave per row, 16 rows/block ----------
        const int r = blockIdx.x * 16 + wave;              // 0..2047
        const float* x = slog + r * NCLS;
        const float* y = tlog + r * NCLS;
        const int label = tgt[r * 8];                      // start indirect chain early
        const bool has2 = lane < (NCLS - 64);
        float x1 = x[lane];
        float y1 = y[lane];
        float x2 = has2 ? x[lane + 64] : -3.0e38f;
        float y2 = has2 ? y[lane + 64] : -3.0e38f;
        float xl = x[label];
        float mx = waveMax(fmaxf(x1, x2));
        float my = waveMax(fmaxf(y1, y2));
        float se1  = waveSum(expf(x1 - mx) + (has2 ? expf(x2 - mx) : 0.f));
        float se4s = waveSum(expf((x1 - mx) * 0.25f) + (has2 ? expf((x2 - mx) * 0.25f) : 0.f));
        float e1 = expf((y1 - my) * 0.25f);
        float e2 = has2 ? expf((y2 - my) * 0.25f) : 0.f;
        float se4t = waveSum(e1 + e2);
        float tnum = waveSum(e1 * (y1 - x1) * 0.25f + (has2 ? e2 * (y2 - x2) * 0.25f : 0.f));
        if (lane == 0) {
            float logZ1  = mx + logf(se1);
            float logZ4s = mx * 0.25f + logf(se4s);
            float logZ4t = my * 0.25f + logf(se4t);
            redL[wave * 2]     = logZ1 - xl;
            redL[wave * 2 + 1] = tnum / se4t + logZ4s - logZ4t;
        }
        __syncthreads();
        if (tid < 2) {
            float s = 0.f;
#pragma unroll
            for (int w = 0; w < 16; ++w) s += redL[w * 2 + tid];
            ws[LP_OFF + blockIdx.x * 2 + tid] = s;
        }
    } else {
        // ---------- policy: 4 streams on 4 waves, lane = pair-row ----------
        const int pb = blockIdx.x - NLOGB;                 // 0..15
        if (tid < OK * 32) {
            w1s4[tid] = ((const float4*)W1)[tid];
            w2s4[tid] = ((const float4*)W2)[tid];
        }
        if (tid < 320) bkt[tid] = 0.f;
        __syncthreads();

        if (wave < 4) {
            // stream: 0 -> As = f1s . W2[:, :64]   1 -> Bs = f2s . W2[:, 64:]
            //         2 -> At = f1t . W1[:, :64]   3 -> Bt = f2t . W1[:, 64:]
            const int i = pb * 64 + lane;                  // pair-row 0..1023
            const float* fbase = (wave & 2) ? tpol : spol;
            const float4* feat = (const float4*)(fbase + (2 * i + (wave & 1)) * FHALF);
            const float4* wb   = (wave & 2) ? w1s4 : w2s4;
            const int colOff   = (wave & 1) ? 16 : 0;

            float acc[OK];
#pragma unroll
            for (int k = 0; k < OK; ++k) acc[k] = 0.f;
            for (int f4 = 0; f4 < FHALF / 4; ++f4) {
                float4 fv = feat[f4];
#pragma unroll
                for (int k = 0; k < OK; ++k) {
                    // wave-uniform LDS address -> broadcast ds_read_b128;
                    // only ~15 live VGPRs here so many reads stay in flight
                    const float4 wv = wb[k * 32 + colOff + f4];
                    acc[k] = fmaf(fv.x, wv.x, acc[k]);
                    acc[k] = fmaf(fv.y, wv.y, acc[k]);
                    acc[k] = fmaf(fv.z, wv.z, acc[k]);
                    acc[k] = fmaf(fv.w, wv.w, acc[k]);
                }
            }
#pragma unroll
            for (int k = 0; k < OK; ++k)
                res[(wave * OK + k) * 64 + lane] = acc[k];  // stride-1: conflict-free
        }
        __syncthreads();

        if (wave < OK) {
            // wave k computes the 8 closed-form stats for output k over 64 rows
            const int k = wave;
            float A = res[(0 * OK + k) * 64 + lane];   // As
            float B = res[(1 * OK + k) * 64 + lane];   // Bs
            float C = res[(2 * OK + k) * 64 + lane];   // At
            float D = res[(3 * OK + k) * 64 + lane];   // Bt
            float du = B - D, dw = A - C;
            float v0 = waveSum(du),  v1 = waveSum(du * du);
            float v2 = waveSum(dw),  v3 = waveSum(dw * dw);
            float v4 = waveSum(B),   v5 = waveSum(B * B);
            float v6 = waveSum(A),   v7 = waveSum(A * A);
            if (lane == 0) {
                float* p = ws + PS_OFF + pb * 72 + k * 8;
                p[0] = v0; p[1] = v1; p[2] = v2; p[3] = v3;
                p[4] = v4; p[5] = v5; p[6] = v6; p[7] = v7;
            }
        }
        if (wave == 9) {
            // bucket pass: lane = pair-row, 32 LDS atomics per lane
            const int i = pb * 64 + lane;
            const int4* t1q = (const int4*)(tgt + (2 * i) * 8);
            const int4* t2q = (const int4*)(tgt + (2 * i + 1) * 8);
            int4 t1a = t1q[0], t1b = t1q[1];
            int4 t2a = t2q[0], t2b = t2q[1];
            int t1[8] = { t1a.x, t1a.y, t1a.z, t1a.w, t1b.x, t1b.y, t1b.z, t1b.w };
            int t2[8] = { t2a.x, t2a.y, t2a.z, t2a.w, t2b.x, t2b.y, t2b.z, t2b.w };
#pragma unroll
            for (int c0 = 0; c0 < 8; ++c0) {
                atomicAdd(&bkt[0 * 80 + c0 * 10 + t1[c0]], 1.0f);
                atomicAdd(&bkt[1 * 80 + c0 * 10 + t2[c0]], 1.0f);
                atomicAdd(&bkt[2 * 80 + c0 * 10 + t1[c0]], res[(0 * OK + c0 + 1) * 64 + lane]);
                atomicAdd(&bkt[3 * 80 + c0 * 10 + t2[c0]], res[(1 * OK + c0 + 1) * 64 + lane]);
            }
        }
        __syncthreads();
        if (tid < 320) ws[PB_OFF + pb * 320 + tid] = bkt[tid];
    }

    // ---------- last-block combine (replaces the second kernel launch) ----------
    __syncthreads();
    if (tid == 0) {
        __threadfence();                       // release: ws stores visible device-wide
        int old = atomicAdd(&g_arrive, 1);
        int last = (old == NBLK - 1);
        if (last) {
            g_arrive = 0;                      // re-arm for next launch / graph replay
            __threadfence();                   // acquire before ws reads
        }
        lastFlag = last;
    }
    __syncthreads();
    if (!lastFlag) return;

    // --- combine phase, executed by the single last-arriving block ---
    float ce = 0.f, kl = 0.f;
    if (tid < NLOGB) {
        ce = ws[LP_OFF + tid * 2];
        kl = ws[LP_OFF + tid * 2 + 1];
    }
    ce = waveSum(ce); kl = waveSum(kl);
    if (lane == 0 && wave < 2) { cekl[wave * 2] = ce; cekl[wave * 2 + 1] = kl; }

    if (tid < 72) {
        float s = 0.f;
#pragma unroll
        for (int b = 0; b < NPOLB; ++b) s += ws[PS_OFF + b * 72 + tid];
        statsC[tid] = s;
    }
    if (tid < 320) {
        float s = 0.f;
#pragma unroll
        for (int b = 0; b < NPOLB; ++b) s += ws[PB_OFF + b * 320 + tid];
        bktC[tid] = s;
    }
    __syncthreads();

    if (tid == 0) {
        const double N = 1024.0, M = 1048576.0;
        double ce_main = (double)(cekl[0] + cekl[2]) / (double)BATCH_;
        double kl_main = (double)(cekl[1] + cekl[3]) * 16.0
                       / (double)(BATCH_ * NCLS);

        double kl_pol = 0.0, Sp_acc = 0.0;
        double SumL[OK], SumL2[OK];
        for (int k = 0; k < OK; ++k) {
            const float* p = &statsC[k * 8];
            double D1u = p[0], D2u = p[1], D1w = p[2], D2w = p[3];
            double U1 = p[4], U2 = p[5], Wa1 = p[6], Wa2 = p[7];
            double cd = (double)bias2[k] - (double)bias1[k];
            double b  = (double)bias2[k];
            double S = N * D2u + N * (D2w + 2.0 * cd * D1w + N * cd * cd)
                     + 2.0 * D1u * (D1w + N * cd);
            if (k == 0)      kl_pol += S / M;
            else if (k == 1) kl_pol += 0.5 * S / M;
            else             Sp_acc += S;
            SumL[k]  = N * U1 + N * Wa1 + M * b;
            SumL2[k] = N * U2 + N * (Wa2 + 2.0 * b * Wa1 + N * b * b)
                     + 2.0 * U1 * (Wa1 + N * b);
        }
        kl_pol += 0.001 * Sp_acc / (7.0 * M);

        double ce_I = -((double)statsC[4] + (double)statsC[6] + N * (double)bias2[0]) / M;

        const float* cnt1 = &bktC[0];
        const float* cnt2 = &bktC[80];
        const float* sA   = &bktC[160];
        const float* sB   = &bktC[240];
        double ce_C = 0.0, ceP = 0.0;
        for (int c0 = 0; c0 < 8; ++c0) {
            double ms = 0.0, pc = 0.0;
            for (int v = 0; v < 10; ++v) {
                double c1 = (double)cnt1[c0 * 10 + v], c2 = (double)cnt2[c0 * 10 + v];
                ms += c1 * (double)sB[c0 * 10 + v] + c2 * (double)sA[c0 * 10 + v];
                pc += c1 * c2;
            }
            ms += (double)bias2[c0 + 1] * pc;
            if (c0 == 0) {
                ce_C = -0.5 * ms / M;
            } else {
                int k = c0 + 1;
                double sg = 2.0 * ms - SumL[k];
                ceP += SumL2[k] - 2.0 * sg + M;
            }
        }
        ceP *= 0.001 / (7.0 * M);

        out[0] = (float)(ce_main + kl_main + kl_pol + ce_I + ce_C + ceP);
    }
}

extern "C" void kernel_launch(void* const* d_in, const int* in_sizes, int n_in,
                              void* d_out, int out_size, void* d_ws, size_t ws_size,
                              hipStream_t stream) {
    const float* slog = (const float*)d_in[0];
    const float* tlog = (const float*)d_in[1];
    const float* spol = (const float*)d_in[2];
    const float* tpol = (const float*)d_in[3];
    const float* W1   = (const float*)d_in[4];
    const float* b1   = (const float*)d_in[5];
    const float* W2   = (const float*)d_in[6];
    const float* b2   = (const float*)d_in[7];
    const int*   tgt  = (const int*)d_in[8];
    float* ws = (float*)d_ws;

    fused_kernel<<<NBLK, 1024, 0, stream>>>(slog, tlog, spol, tpol, W1, W2, tgt,
                                            b1, b2, ws, (float*)d_out);
}

// Round 4
// 85.566 us; speedup vs baseline: 1.2597x; 1.0263x over previous
//
#include <hip/hip_runtime.h>
#include <math.h>

// Problem constants
#define NCLS   100
#define BATCH_ 2048
#define OK     9        // POLICY_NUMS + 2
#define FHALF  64       // FEATURE_NUMS / 2

#define NLOGB  128      // logits blocks: 1024 thr = 16 waves, 1 row/wave
#define NPOLB  16       // policy blocks: 64 pair-rows each, 4 streams on waves 0-3
#define NBLK   (NLOGB + NPOLB)

// Workspace layout (floats). Every slot below is written exactly once by its
// owning block (plain stores); the last-arriving block reduces.
#define LP_OFF 0                        // 128 x {ce, kl}
#define PS_OFF (LP_OFF + NLOGB * 2)     // 16 x 72 policy stats
#define PB_OFF (PS_OFF + NPOLB * 72)    // 16 x 320 policy buckets

// Module-scope arrival counter: init 0 at module load; last block resets it
// before combining so graph replays start clean. Not in d_ws (poison-safe).
__device__ int g_arrive = 0;

__device__ __forceinline__ float waveSum(float v) {
#pragma unroll
    for (int off = 32; off; off >>= 1) v += __shfl_xor(v, off, 64);
    return v;
}
__device__ __forceinline__ float waveMax(float v) {
#pragma unroll
    for (int off = 32; off; off >>= 1) v = fmaxf(v, __shfl_xor(v, off, 64));
    return v;
}

__global__ __launch_bounds__(1024) void fused_kernel(
        const float* __restrict__ slog, const float* __restrict__ tlog,
        const float* __restrict__ spol, const float* __restrict__ tpol,
        const float* __restrict__ W1,   const float* __restrict__ W2,
        const int*   __restrict__ tgt,
        const float* __restrict__ bias1, const float* __restrict__ bias2,
        float* __restrict__ ws, float* __restrict__ out)
{
    // policy-phase LDS
    __shared__ float4 w1s4[OK * 32];        // [OK][32] float4 = [OK][128] floats
    __shared__ float4 w2s4[OK * 32];
    __shared__ float  res[4 * OK * 64];     // [stream][k][lane] per-row dot results
    __shared__ float  bkt[320];
    __shared__ float  redL[32];
    // combine-phase scratch (only the last block uses these)
    __shared__ float  statsC[72];
    __shared__ float  bktC[320];
    __shared__ float  cekl[8];
    __shared__ double SumLs[OK], SumL2s[OK], klArr[OK], ceArr[8];
    __shared__ int    lastFlag;

    const int tid  = threadIdx.x;
    const int wave = tid >> 6;
    const int lane = tid & 63;

    if (blockIdx.x < NLOGB) {
        // ---------- logits: CE + KL(T=4), one wave per row, 16 rows/block ----------
        const int r = blockIdx.x * 16 + wave;              // 0..2047
        const float* x = slog + r * NCLS;
        const float* y = tlog + r * NCLS;
        const int label = tgt[r * 8];                      // start indirect chain early
        const bool has2 = lane < (NCLS - 64);
        float x1 = x[lane];
        float y1 = y[lane];
        float x2 = has2 ? x[lane + 64] : -3.0e38f;
        float y2 = has2 ? y[lane + 64] : -3.0e38f;
        float xl = x[label];
        float mx = waveMax(fmaxf(x1, x2));
        float my = waveMax(fmaxf(y1, y2));
        float se1  = waveSum(expf(x1 - mx) + (has2 ? expf(x2 - mx) : 0.f));
        float se4s = waveSum(expf((x1 - mx) * 0.25f) + (has2 ? expf((x2 - mx) * 0.25f) : 0.f));
        float e1 = expf((y1 - my) * 0.25f);
        float e2 = has2 ? expf((y2 - my) * 0.25f) : 0.f;
        float se4t = waveSum(e1 + e2);
        float tnum = waveSum(e1 * (y1 - x1) * 0.25f + (has2 ? e2 * (y2 - x2) * 0.25f : 0.f));
        if (lane == 0) {
            float logZ1  = mx + logf(se1);
            float logZ4s = mx * 0.25f + logf(se4s);
            float logZ4t = my * 0.25f + logf(se4t);
            redL[wave * 2]     = logZ1 - xl;
            redL[wave * 2 + 1] = tnum / se4t + logZ4s - logZ4t;
        }
        __syncthreads();
        if (wave == 0) {
            // redL[2w+c]: sum over w via xor {2,4,8,16}; parity bit keeps ce/kl apart
            float v = (lane < 32) ? redL[lane] : 0.f;
            v += __shfl_xor(v, 2, 64);
            v += __shfl_xor(v, 4, 64);
            v += __shfl_xor(v, 8, 64);
            v += __shfl_xor(v, 16, 64);
            if (lane < 2) ws[LP_OFF + blockIdx.x * 2 + lane] = v;
        }
    } else {
        // ---------- policy: 4 streams on 4 waves, lane = pair-row ----------
        const int pb = blockIdx.x - NLOGB;                 // 0..15
        if (tid < OK * 32) {
            w1s4[tid] = ((const float4*)W1)[tid];
            w2s4[tid] = ((const float4*)W2)[tid];
        }
        if (tid < 320) bkt[tid] = 0.f;
        __syncthreads();

        if (wave < 4) {
            // stream: 0 -> As = f1s . W2[:, :64]   1 -> Bs = f2s . W2[:, 64:]
            //         2 -> At = f1t . W1[:, :64]   3 -> Bt = f2t . W1[:, 64:]
            const int i = pb * 64 + lane;                  // pair-row 0..1023
            const float* fbase = (wave & 2) ? tpol : spol;
            const float4* feat = (const float4*)(fbase + (2 * i + (wave & 1)) * FHALF);
            const float4* wb   = (wave & 2) ? w1s4 : w2s4;
            const int colOff   = (wave & 1) ? 16 : 0;

            float acc[OK];
#pragma unroll
            for (int k = 0; k < OK; ++k) acc[k] = 0.f;
#pragma unroll 4
            for (int f4 = 0; f4 < FHALF / 4; ++f4) {
                float4 fv = feat[f4];
#pragma unroll
                for (int k = 0; k < OK; ++k) {
                    // wave-uniform LDS address -> broadcast ds_read_b128
                    const float4 wv = wb[k * 32 + colOff + f4];
                    acc[k] = fmaf(fv.x, wv.x, acc[k]);
                    acc[k] = fmaf(fv.y, wv.y, acc[k]);
                    acc[k] = fmaf(fv.z, wv.z, acc[k]);
                    acc[k] = fmaf(fv.w, wv.w, acc[k]);
                }
            }
#pragma unroll
            for (int k = 0; k < OK; ++k)
                res[(wave * OK + k) * 64 + lane] = acc[k];  // stride-1: conflict-free
        }
        __syncthreads();

        if (wave < OK) {
            // wave k computes the 8 closed-form stats for output k over 64 rows
            const int k = wave;
            float A = res[(0 * OK + k) * 64 + lane];   // As
            float B = res[(1 * OK + k) * 64 + lane];   // Bs
            float C = res[(2 * OK + k) * 64 + lane];   // At
            float D = res[(3 * OK + k) * 64 + lane];   // Bt
            float du = B - D, dw = A - C;
            float v0 = waveSum(du),  v1 = waveSum(du * du);
            float v2 = waveSum(dw),  v3 = waveSum(dw * dw);
            float v4 = waveSum(B),   v5 = waveSum(B * B);
            float v6 = waveSum(A),   v7 = waveSum(A * A);
            if (lane == 0) {
                float* p = ws + PS_OFF + pb * 72 + k * 8;
                p[0] = v0; p[1] = v1; p[2] = v2; p[3] = v3;
                p[4] = v4; p[5] = v5; p[6] = v6; p[7] = v7;
            }
        }
        if (wave >= 8) {
            // buckets: wave 8..15 handles c0 = wave-8; 4 LDS atomics per lane
            const int c0 = wave - 8;
            const int i  = pb * 64 + lane;
            const int t1 = tgt[(2 * i) * 8 + c0];
            const int t2 = tgt[(2 * i + 1) * 8 + c0];
            atomicAdd(&bkt[0 * 80 + c0 * 10 + t1], 1.0f);
            atomicAdd(&bkt[1 * 80 + c0 * 10 + t2], 1.0f);
            atomicAdd(&bkt[2 * 80 + c0 * 10 + t1], res[(0 * OK + c0 + 1) * 64 + lane]);
            atomicAdd(&bkt[3 * 80 + c0 * 10 + t2], res[(1 * OK + c0 + 1) * 64 + lane]);
        }
        __syncthreads();
        if (tid < 320) ws[PB_OFF + pb * 320 + tid] = bkt[tid];
    }

    // ---------- last-block combine (replaces the second kernel launch) ----------
    __syncthreads();
    if (tid == 0) {
        __threadfence();                       // release: ws stores visible device-wide
        int old = atomicAdd(&g_arrive, 1);
        int last = (old == NBLK - 1);
        if (last) {
            g_arrive = 0;                      // re-arm for next launch / graph replay
            __threadfence();                   // acquire before ws reads
        }
        lastFlag = last;
    }
    __syncthreads();
    if (!lastFlag) return;

    // --- combine phase, executed by the single last-arriving block ---
    float ce = 0.f, kl = 0.f;
    if (tid < NLOGB) {
        ce = ws[LP_OFF + tid * 2];
        kl = ws[LP_OFF + tid * 2 + 1];
    }
    ce = waveSum(ce); kl = waveSum(kl);
    if (lane == 0 && wave < 2) { cekl[wave * 2] = ce; cekl[wave * 2 + 1] = kl; }

    if (tid < 72) {
        float s = 0.f;
#pragma unroll
        for (int b = 0; b < NPOLB; ++b) s += ws[PS_OFF + b * 72 + tid];
        statsC[tid] = s;
    }
    if (tid < 320) {
        float s = 0.f;
#pragma unroll
        for (int b = 0; b < NPOLB; ++b) s += ws[PB_OFF + b * 320 + tid];
        bktC[tid] = s;
    }
    __syncthreads();

    const double N = 1024.0, M = 1048576.0;

    // Phase A: lane k = tid < 9 computes per-output stats
    if (tid < OK) {
        const int k = tid;
        const float* p = &statsC[k * 8];
        double D1u = p[0], D2u = p[1], D1w = p[2], D2w = p[3];
        double U1 = p[4], U2 = p[5], Wa1 = p[6], Wa2 = p[7];
        double cd = (double)bias2[k] - (double)bias1[k];
        double b  = (double)bias2[k];
        double S = N * D2u + N * (D2w + 2.0 * cd * D1w + N * cd * cd)
                 + 2.0 * D1u * (D1w + N * cd);
        klArr[k] = (k == 0) ? S / M
                 : (k == 1) ? 0.5 * S / M
                 : 0.001 * S / (7.0 * M);
        SumLs[k]  = N * U1 + N * Wa1 + M * b;
        SumL2s[k] = N * U2 + N * (Wa2 + 2.0 * b * Wa1 + N * b * b)
                  + 2.0 * U1 * (Wa1 + N * b);
    }
    __syncthreads();

    // Phase B: lane c0 = tid < 8 computes bucket dot-products
    if (tid < 8) {
        const int c0 = tid;
        const float* cnt1 = &bktC[0];
        const float* cnt2 = &bktC[80];
        const float* sA   = &bktC[160];
        const float* sB   = &bktC[240];
        double ms = 0.0, pc = 0.0;
        for (int v = 0; v < 10; ++v) {
            double c1 = (double)cnt1[c0 * 10 + v], c2 = (double)cnt2[c0 * 10 + v];
            ms += c1 * (double)sB[c0 * 10 + v] + c2 * (double)sA[c0 * 10 + v];
            pc += c1 * c2;
        }
        ms += (double)bias2[c0 + 1] * pc;
        if (c0 == 0) {
            ceArr[0] = -0.5 * ms / M;
        } else {
            const int k = c0 + 1;
            double sg = 2.0 * ms - SumLs[k];
            ceArr[c0] = (SumL2s[k] - 2.0 * sg + M) * (0.001 / (7.0 * M));
        }
    }
    __syncthreads();

    // Phase C: short serial tail on lane 0
    if (tid == 0) {
        double ce_main = (double)(cekl[0] + cekl[2]) / (double)BATCH_;
        double kl_main = (double)(cekl[1] + cekl[3]) * 16.0
                       / (double)(BATCH_ * NCLS);
        double kl_pol = 0.0;
        for (int k = 0; k < OK; ++k) kl_pol += klArr[k];
        double ce_I = -((double)statsC[4] + (double)statsC[6] + N * (double)bias2[0]) / M;
        double ce_C = ceArr[0];
        double ceP = 0.0;
        for (int c0 = 1; c0 < 8; ++c0) ceP += ceArr[c0];
        out[0] = (float)(ce_main + kl_main + kl_pol + ce_I + ce_C + ceP);
    }
}

extern "C" void kernel_launch(void* const* d_in, const int* in_sizes, int n_in,
                              void* d_out, int out_size, void* d_ws, size_t ws_size,
                              hipStream_t stream) {
    const float* slog = (const float*)d_in[0];
    const float* tlog = (const float*)d_in[1];
    const float* spol = (const float*)d_in[2];
    const float* tpol = (const float*)d_in[3];
    const float* W1   = (const float*)d_in[4];
    const float* b1   = (const float*)d_in[5];
    const float* W2   = (const float*)d_in[6];
    const float* b2   = (const float*)d_in[7];
    const int*   tgt  = (const int*)d_in[8];
    float* ws = (float*)d_ws;

    fused_kernel<<<NBLK, 1024, 0, stream>>>(slog, tlog, spol, tpol, W1, W2, tgt,
                                            b1, b2, ws, (float*)d_out);
}

// Round 5
// 81.986 us; speedup vs baseline: 1.3147x; 1.0437x over previous
//
#include <hip/hip_runtime.h>
#include <math.h>

// Problem constants
#define NCLS   100
#define BATCH_ 2048
#define OK     9        // POLICY_NUMS + 2
#define FHALF  64       // FEATURE_NUMS / 2

#define NLOGB  64       // logits blocks: 1024 thr = 16 waves, 2 rows/wave
#define NPOLB  16       // policy blocks: 64 pair-rows each, 4 streams on waves 0-3
#define NBLK   (NLOGB + NPOLB)

// Workspace layout (floats). Every slot below is written exactly once by its
// owning block (plain stores); the last-arriving block reduces.
#define LP_OFF 0                        // 64 x {ce, kl}
#define PS_OFF (LP_OFF + NLOGB * 2)     // 16 x 72 policy stats
#define PB_OFF (PS_OFF + NPOLB * 72)    // 16 x 320 policy buckets

// Module-scope arrival counter: init 0 at module load; last block resets it
// before combining so graph replays start clean. Not in d_ws (poison-safe).
__device__ int g_arrive = 0;

__device__ __forceinline__ float waveSum(float v) {
#pragma unroll
    for (int off = 32; off; off >>= 1) v += __shfl_xor(v, off, 64);
    return v;
}
__device__ __forceinline__ float waveMax(float v) {
#pragma unroll
    for (int off = 32; off; off >>= 1) v = fmaxf(v, __shfl_xor(v, off, 64));
    return v;
}

__global__ __launch_bounds__(1024) void fused_kernel(
        const float* __restrict__ slog, const float* __restrict__ tlog,
        const float* __restrict__ spol, const float* __restrict__ tpol,
        const float* __restrict__ W1,   const float* __restrict__ W2,
        const int*   __restrict__ tgt,
        const float* __restrict__ bias1, const float* __restrict__ bias2,
        float* __restrict__ ws, float* __restrict__ out)
{
    // policy-phase LDS
    __shared__ float4 w1s4[OK * 32];        // [OK][32] float4 = [OK][128] floats
    __shared__ float4 w2s4[OK * 32];
    __shared__ float  res[4 * OK * 64];     // [stream][k][lane] per-row dot results
    __shared__ float  bkt[320];
    __shared__ float  redL[64];             // 16 waves x {ce0, kl0, ce1, kl1}
    // combine-phase scratch (only the last block uses these)
    __shared__ float  statsC[72];
    __shared__ float  bktC[320];
    __shared__ float  cekl[2];
    __shared__ double SumLs[OK], SumL2s[OK], klArr[OK], ceArr[8];
    __shared__ int    lastFlag;

    const int tid  = threadIdx.x;
    const int wave = tid >> 6;
    const int lane = tid & 63;

    if (blockIdx.x < NLOGB) {
        // ---------- logits: CE + KL(T=4), TWO rows per wave (ILP), 32 rows/block ----
        const int r0 = blockIdx.x * 32 + wave * 2;         // 0..2046
        const float* xa = slog + r0 * NCLS;
        const float* ya = tlog + r0 * NCLS;
        const float* xb = xa + NCLS;
        const float* yb = ya + NCLS;
        const int lab0 = tgt[r0 * 8];                      // start indirect chains early
        const int lab1 = tgt[(r0 + 1) * 8];
        const bool has2 = lane < (NCLS - 64);
        // row 0 loads
        float a1 = xa[lane], a2 = has2 ? xa[lane + 64] : -3.0e38f;
        float b1 = ya[lane], b2 = has2 ? ya[lane + 64] : -3.0e38f;
        // row 1 loads
        float c1 = xb[lane], c2 = has2 ? xb[lane + 64] : -3.0e38f;
        float d1 = yb[lane], d2 = has2 ? yb[lane + 64] : -3.0e38f;
        float xl0 = xa[lab0], xl1 = xb[lab1];

        // the 4 max chains and later sum chains for the two rows are
        // independent -> shuffle latency overlaps across rows
        float mxa = waveMax(fmaxf(a1, a2));
        float mxb = waveMax(fmaxf(b1, b2));
        float mxc = waveMax(fmaxf(c1, c2));
        float mxd = waveMax(fmaxf(d1, d2));

        float se1_0  = waveSum(expf(a1 - mxa) + (has2 ? expf(a2 - mxa) : 0.f));
        float se4s_0 = waveSum(expf((a1 - mxa) * 0.25f) + (has2 ? expf((a2 - mxa) * 0.25f) : 0.f));
        float e1_0 = expf((b1 - mxb) * 0.25f);
        float e2_0 = has2 ? expf((b2 - mxb) * 0.25f) : 0.f;
        float se4t_0 = waveSum(e1_0 + e2_0);
        float tnum_0 = waveSum(e1_0 * (b1 - a1) * 0.25f + (has2 ? e2_0 * (b2 - a2) * 0.25f : 0.f));

        float se1_1  = waveSum(expf(c1 - mxc) + (has2 ? expf(c2 - mxc) : 0.f));
        float se4s_1 = waveSum(expf((c1 - mxc) * 0.25f) + (has2 ? expf((c2 - mxc) * 0.25f) : 0.f));
        float e1_1 = expf((d1 - mxd) * 0.25f);
        float e2_1 = has2 ? expf((d2 - mxd) * 0.25f) : 0.f;
        float se4t_1 = waveSum(e1_1 + e2_1);
        float tnum_1 = waveSum(e1_1 * (d1 - c1) * 0.25f + (has2 ? e2_1 * (d2 - c2) * 0.25f : 0.f));

        if (lane == 0) {
            redL[wave * 4 + 0] = (mxa + logf(se1_0)) - xl0;
            redL[wave * 4 + 1] = tnum_0 / se4t_0 + (mxa * 0.25f + logf(se4s_0))
                               - (mxb * 0.25f + logf(se4t_0 * 0.f + se4t_0));  // placeholder avoided below
        }
        // NOTE: compute kl terms without tricks (overwrite cleanly):
        if (lane == 0) {
            float logZ4s_0 = mxa * 0.25f + logf(se4s_0);
            float logZ4t_0 = mxb * 0.25f + logf(se4t_0);
            redL[wave * 4 + 1] = tnum_0 / se4t_0 + logZ4s_0 - logZ4t_0;
            redL[wave * 4 + 2] = (mxc + logf(se1_1)) - xl1;
            float logZ4s_1 = mxc * 0.25f + logf(se4s_1);
            float logZ4t_1 = mxd * 0.25f + logf(se4t_1);
            redL[wave * 4 + 3] = tnum_1 / se4t_1 + logZ4s_1 - logZ4t_1;
        }
        __syncthreads();
        if (wave == 0) {
            // lane L holds redL[L]; xor {4,8,16,32} sums same (L&3) residue over
            // the 16 waves; final xor 2 folds row0+row1 -> lane0=ce, lane1=kl
            float v = redL[lane];
            v += __shfl_xor(v, 4, 64);
            v += __shfl_xor(v, 8, 64);
            v += __shfl_xor(v, 16, 64);
            v += __shfl_xor(v, 32, 64);
            v += __shfl_xor(v, 2, 64);
            if (lane < 2) ws[LP_OFF + blockIdx.x * 2 + lane] = v;
        }
    } else {
        // ---------- policy: 4 streams on 4 waves, lane = pair-row ----------
        const int pb = blockIdx.x - NLOGB;                 // 0..15
        if (tid < OK * 32) {
            w1s4[tid] = ((const float4*)W1)[tid];
            w2s4[tid] = ((const float4*)W2)[tid];
        }
        if (tid < 320) bkt[tid] = 0.f;
        __syncthreads();

        if (wave < 4) {
            // stream: 0 -> As = f1s . W2[:, :64]   1 -> Bs = f2s . W2[:, 64:]
            //         2 -> At = f1t . W1[:, :64]   3 -> Bt = f2t . W1[:, 64:]
            const int i = pb * 64 + lane;                  // pair-row 0..1023
            const float* fbase = (wave & 2) ? tpol : spol;
            const float4* feat = (const float4*)(fbase + (2 * i + (wave & 1)) * FHALF);
            const float4* wb   = (wave & 2) ? w1s4 : w2s4;
            const int colOff   = (wave & 1) ? 16 : 0;

            float acc[OK];
#pragma unroll
            for (int k = 0; k < OK; ++k) acc[k] = 0.f;
#pragma unroll 4
            for (int f4 = 0; f4 < FHALF / 4; ++f4) {
                float4 fv = feat[f4];
#pragma unroll
                for (int k = 0; k < OK; ++k) {
                    // wave-uniform LDS address -> broadcast ds_read_b128
                    const float4 wv = wb[k * 32 + colOff + f4];
                    acc[k] = fmaf(fv.x, wv.x, acc[k]);
                    acc[k] = fmaf(fv.y, wv.y, acc[k]);
                    acc[k] = fmaf(fv.z, wv.z, acc[k]);
                    acc[k] = fmaf(fv.w, wv.w, acc[k]);
                }
            }
#pragma unroll
            for (int k = 0; k < OK; ++k)
                res[(wave * OK + k) * 64 + lane] = acc[k];  // stride-1: conflict-free
        }
        __syncthreads();

        if (wave < OK) {
            // wave k computes the 8 closed-form stats for output k over 64 rows
            const int k = wave;
            float A = res[(0 * OK + k) * 64 + lane];   // As
            float B = res[(1 * OK + k) * 64 + lane];   // Bs
            float C = res[(2 * OK + k) * 64 + lane];   // At
            float D = res[(3 * OK + k) * 64 + lane];   // Bt
            float du = B - D, dw = A - C;
            float v0 = waveSum(du),  v1 = waveSum(du * du);
            float v2 = waveSum(dw),  v3 = waveSum(dw * dw);
            float v4 = waveSum(B),   v5 = waveSum(B * B);
            float v6 = waveSum(A),   v7 = waveSum(A * A);
            if (lane == 0) {
                float* p = ws + PS_OFF + pb * 72 + k * 8;
                p[0] = v0; p[1] = v1; p[2] = v2; p[3] = v3;
                p[4] = v4; p[5] = v5; p[6] = v6; p[7] = v7;
            }
        }
        if (wave >= 8) {
            // buckets: wave 8..15 handles c0 = wave-8; 4 LDS atomics per lane
            const int c0 = wave - 8;
            const int i  = pb * 64 + lane;
            const int t1 = tgt[(2 * i) * 8 + c0];
            const int t2 = tgt[(2 * i + 1) * 8 + c0];
            atomicAdd(&bkt[0 * 80 + c0 * 10 + t1], 1.0f);
            atomicAdd(&bkt[1 * 80 + c0 * 10 + t2], 1.0f);
            atomicAdd(&bkt[2 * 80 + c0 * 10 + t1], res[(0 * OK + c0 + 1) * 64 + lane]);
            atomicAdd(&bkt[3 * 80 + c0 * 10 + t2], res[(1 * OK + c0 + 1) * 64 + lane]);
        }
        __syncthreads();
        if (tid < 320) ws[PB_OFF + pb * 320 + tid] = bkt[tid];
    }

    // ---------- last-block combine (replaces the second kernel launch) ----------
    __syncthreads();
    if (tid == 0) {
        __threadfence();                       // release: ws stores visible device-wide
        int old = atomicAdd(&g_arrive, 1);
        int last = (old == NBLK - 1);
        if (last) {
            g_arrive = 0;                      // re-arm for next launch / graph replay
            __threadfence();                   // acquire before ws reads
        }
        lastFlag = last;
    }
    __syncthreads();
    if (!lastFlag) return;

    // --- combine phase, executed by the single last-arriving block ---
    float ce = 0.f, kl = 0.f;
    if (tid < NLOGB) {                        // 64 entries -> wave 0 only
        ce = ws[LP_OFF + tid * 2];
        kl = ws[LP_OFF + tid * 2 + 1];
    }
    ce = waveSum(ce); kl = waveSum(kl);
    if (tid == 0) { cekl[0] = ce; cekl[1] = kl; }

    if (tid < 72) {
        float s = 0.f;
#pragma unroll
        for (int b = 0; b < NPOLB; ++b) s += ws[PS_OFF + b * 72 + tid];
        statsC[tid] = s;
    }
    if (tid < 320) {
        float s = 0.f;
#pragma unroll
        for (int b = 0; b < NPOLB; ++b) s += ws[PB_OFF + b * 320 + tid];
        bktC[tid] = s;
    }
    __syncthreads();

    const double N = 1024.0, M = 1048576.0;

    // Phase A: lane k = tid < 9 computes per-output stats
    if (tid < OK) {
        const int k = tid;
        const float* p = &statsC[k * 8];
        double D1u = p[0], D2u = p[1], D1w = p[2], D2w = p[3];
        double U1 = p[4], U2 = p[5], Wa1 = p[6], Wa2 = p[7];
        double cd = (double)bias2[k] - (double)bias1[k];
        double b  = (double)bias2[k];
        double S = N * D2u + N * (D2w + 2.0 * cd * D1w + N * cd * cd)
                 + 2.0 * D1u * (D1w + N * cd);
        klArr[k] = (k == 0) ? S / M
                 : (k == 1) ? 0.5 * S / M
                 : 0.001 * S / (7.0 * M);
        SumLs[k]  = N * U1 + N * Wa1 + M * b;
        SumL2s[k] = N * U2 + N * (Wa2 + 2.0 * b * Wa1 + N * b * b)
                  + 2.0 * U1 * (Wa1 + N * b);
    }
    __syncthreads();

    // Phase B: lane c0 = tid < 8 computes bucket dot-products
    if (tid < 8) {
        const int c0 = tid;
        const float* cnt1 = &bktC[0];
        const float* cnt2 = &bktC[80];
        const float* sA   = &bktC[160];
        const float* sB   = &bktC[240];
        double ms = 0.0, pc = 0.0;
        for (int v = 0; v < 10; ++v) {
            double c1 = (double)cnt1[c0 * 10 + v], c2 = (double)cnt2[c0 * 10 + v];
            ms += c1 * (double)sB[c0 * 10 + v] + c2 * (double)sA[c0 * 10 + v];
            pc += c1 * c2;
        }
        ms += (double)bias2[c0 + 1] * pc;
        if (c0 == 0) {
            ceArr[0] = -0.5 * ms / M;
        } else {
            const int k = c0 + 1;
            double sg = 2.0 * ms - SumLs[k];
            ceArr[c0] = (SumL2s[k] - 2.0 * sg + M) * (0.001 / (7.0 * M));
        }
    }
    __syncthreads();

    // Phase C: short serial tail on lane 0
    if (tid == 0) {
        double ce_main = (double)cekl[0] / (double)BATCH_;
        double kl_main = (double)cekl[1] * 16.0 / (double)(BATCH_ * NCLS);
        double kl_pol = 0.0;
        for (int k = 0; k < OK; ++k) kl_pol += klArr[k];
        double ce_I = -((double)statsC[4] + (double)statsC[6] + N * (double)bias2[0]) / M;
        double ce_C = ceArr[0];
        double ceP = 0.0;
        for (int c0 = 1; c0 < 8; ++c0) ceP += ceArr[c0];
        out[0] = (float)(ce_main + kl_main + kl_pol + ce_I + ce_C + ceP);
    }
}

extern "C" void kernel_launch(void* const* d_in, const int* in_sizes, int n_in,
                              void* d_out, int out_size, void* d_ws, size_t ws_size,
                              hipStream_t stream) {
    const float* slog = (const float*)d_in[0];
    const float* tlog = (const float*)d_in[1];
    const float* spol = (const float*)d_in[2];
    const float* tpol = (const float*)d_in[3];
    const float* W1   = (const float*)d_in[4];
    const float* b1   = (const float*)d_in[5];
    const float* W2   = (const float*)d_in[6];
    const float* b2   = (const float*)d_in[7];
    const int*   tgt  = (const int*)d_in[8];
    float* ws = (float*)d_ws;

    fused_kernel<<<NBLK, 1024, 0, stream>>>(slog, tlog, spol, tpol, W1, W2, tgt,
                                            b1, b2, ws, (float*)d_out);
}